// Round 3
// baseline (369.534 us; speedup 1.0000x reference)
//
#include <hip/hip_runtime.h>

#define N_NODES 50000
#define N_EDGES 800000
#define ETOT (N_EDGES + N_NODES)
#define DIN 512
#define HID 256
#define NOUT 64
#define SCAN_CHUNK 2048

typedef __attribute__((ext_vector_type(8))) short short8;
typedef __attribute__((ext_vector_type(4))) float f32x4;
typedef __attribute__((ext_vector_type(2))) float f32x2;
typedef __attribute__((ext_vector_type(4))) unsigned short us4;

#define FMA2(a, b, c) __builtin_elementwise_fma((a), (b), (c))

// float -> bf16 bits, round-to-nearest-even
__device__ __forceinline__ unsigned short f2bf(float f) {
  union { float f; unsigned u; } x; x.f = f;
  unsigned r = x.u + 0x7fff + ((x.u >> 16) & 1);
  return (unsigned short)(r >> 16);
}
__device__ __forceinline__ float bf2f(unsigned short b) {
  return __uint_as_float(((unsigned)b) << 16);
}
// u32 holding bf16 pair {elem 2k (lo), elem 2k+1 (hi)} -> float2, 2 VALU ops
__device__ __forceinline__ f32x2 bfpair(unsigned u) {
  f32x2 r;
  r.x = __uint_as_float(u << 16);
  r.y = __uint_as_float(u & 0xffff0000u);
  return r;
}

// address-space casts for global_load_lds
#define AS1(p) ((const __attribute__((address_space(1))) unsigned int*)(p))
#define AS3(p) ((__attribute__((address_space(3))) unsigned int*)(p))

// ---------------- edge index decode (int32 vs int64 hedge) ----------------
__device__ __forceinline__ int edge_at(const void* ei, long long idx, int is32) {
  if (is32) return ((const int*)ei)[idx];
  return (int)((const long long*)ei)[idx];
}

// cursor[i]=1 (self-loop pre-count) + dtype detect (block 0, wave 0 scans
// 2048 int64 samples; lane 0 writes flag exactly once, 0 or 1).
__global__ void initK(const void* ei, int* cursor, int* flag) {
  int i = blockIdx.x * blockDim.x + threadIdx.x;
  if (i < N_NODES) cursor[i] = 1;
  if (blockIdx.x == 0 && threadIdx.x < 64) {
    int lane = threadIdx.x;
    bool bad = false;
#pragma unroll
    for (int j = 0; j < 32; ++j) {
      long long v = ((const long long*)ei)[lane * 32 + j];
      bad |= (v < 0 || v >= N_NODES);
    }
    bool anybad = __any(bad);
    if (lane == 0) *flag = anybad ? 1 : 0;
  }
}

__global__ void histK(const void* ei, const int* flag, int* cursor) {
  int e = blockIdx.x * blockDim.x + threadIdx.x;
  if (e >= N_EDGES) return;
  int f = *flag;
  int d = edge_at(ei, (long long)N_EDGES + e, f);
  atomicAdd(&cursor[d], 1);
}

// ---------------- exclusive scan over counts -> row_ptr ----------------
__global__ void scan1K(const int* counts, int* excl, int* bsums) {
  __shared__ int sdata[256];
  int base = blockIdx.x * SCAN_CHUNK;
  int t = threadIdx.x;
  int local[8];
  int sum = 0;
#pragma unroll
  for (int j = 0; j < 8; ++j) {
    int idx = base + t * 8 + j;
    int v = (idx < N_NODES) ? counts[idx] : 0;
    local[j] = sum;
    sum += v;
  }
  sdata[t] = sum;
  __syncthreads();
  for (int off = 1; off < 256; off <<= 1) {
    int v = (t >= off) ? sdata[t - off] : 0;
    __syncthreads();
    sdata[t] += v;
    __syncthreads();
  }
  int texcl = (t == 0) ? 0 : sdata[t - 1];
#pragma unroll
  for (int j = 0; j < 8; ++j) {
    int idx = base + t * 8 + j;
    if (idx < N_NODES) excl[idx] = texcl + local[j];
  }
  if (t == 255) bsums[blockIdx.x] = sdata[255];
}

__global__ void scan2K(int* bsums, int nb) {
  if (threadIdx.x == 0 && blockIdx.x == 0) {
    int run = 0;
    for (int i = 0; i < nb; ++i) { int v = bsums[i]; bsums[i] = run; run += v; }
  }
}

__global__ void scan3K(int* row_ptr, const int* bsums, int* cursor) {
  int i = blockIdx.x * blockDim.x + threadIdx.x;
  if (i < N_NODES) {
    int v = row_ptr[i] + bsums[i >> 11];
    row_ptr[i] = v;
    cursor[i] = v;
    if (i == 0) row_ptr[N_NODES] = ETOT;
  }
}

__global__ void scatterK(const void* ei, const int* flag, int* cursor, int* col) {
  int e = blockIdx.x * blockDim.x + threadIdx.x;
  if (e < N_EDGES) {
    int f = *flag;
    int s = edge_at(ei, e, f);
    int d = edge_at(ei, (long long)N_EDGES + e, f);
    int pos = atomicAdd(&cursor[d], 1);
    col[pos] = s;
  } else if (e < N_EDGES + N_NODES) {
    int i = e - N_EDGES;
    int pos = atomicAdd(&cursor[i], 1);
    col[pos] = i;
  }
}

// ---------------- fp32 -> bf16 streaming convert: x and w1 ----------------
__global__ __launch_bounds__(256) void cvtK(const float* __restrict__ x,
                                            const float* __restrict__ w1,
                                            unsigned short* __restrict__ xb,
                                            unsigned short* __restrict__ wb) {
  const long long NX = (long long)N_NODES * DIN / 8;  // chunks of 8 floats
  const long long NW = (long long)HID * DIN / 8;
  long long stride = (long long)gridDim.x * blockDim.x;
  for (long long c = (long long)blockIdx.x * blockDim.x + threadIdx.x;
       c < NX + NW; c += stride) {
    const float* src;
    unsigned short* dst;
    if (c < NX) { src = x + c * 8; dst = xb + c * 8; }
    else { src = w1 + (c - NX) * 8; dst = wb + (c - NX) * 8; }
    float4 v0 = ((const float4*)src)[0];
    float4 v1 = ((const float4*)src)[1];
    short8 s;
    s[0] = f2bf(v0.x); s[1] = f2bf(v0.y); s[2] = f2bf(v0.z); s[3] = f2bf(v0.w);
    s[4] = f2bf(v1.x); s[5] = f2bf(v1.y); s[6] = f2bf(v1.z); s[7] = f2bf(v1.w);
    *(short8*)dst = s;
  }
}

// ------- GEMM1 via MFMA from bf16 inputs: h_bf = bf16(relu(xb @ wb^T + b1)) ---
// m97 structure: 128x128 tile, BK=64, global_load_lds width=16 staging with
// pre-swizzled global source (rule #21): LDS linear dest, k-slot of lane =
// (lc ^ lr) so the swizzled ds_read (slot = kgrp ^ (r&7)) lands on the right
// data. Same XOR family as the round-0 kernel which measured 0 bank conflicts.
__global__ __launch_bounds__(256) void gemm1MF(const unsigned short* __restrict__ Ab,
                                               const unsigned short* __restrict__ Bb,
                                               const float* __restrict__ bias,
                                               unsigned short* __restrict__ C) {
  __shared__ short As[128 * 64];  // 16 KB, rows of 64 bf16, 8 slots x 16B
  __shared__ short Bs[128 * 64];
  int t = threadIdx.x;
  int wv = t >> 6, ln = t & 63;
  int wr = wv >> 1, wc = wv & 1;
  int row0 = blockIdx.x * 128;
  int col0 = blockIdx.y * 128;

  // staging: per wave-call, lane ln covers LDS bytes base + ln*16
  // = row (chunk*8 + ln>>3), slot (ln&7). Source fetches k-slot (lc ^ lr).
  int lr = ln >> 3, lc = ln & 7;
  int scol = ((lc ^ lr) << 3);  // element offset within 64-wide K-tile

  int ar0 = row0 + lr;  // + chunk*8 added per call
  const unsigned short* bbase = &Bb[(long long)(col0 + lr) * DIN + scol];

  f32x4 acc[4][4];
#pragma unroll
  for (int mi = 0; mi < 4; ++mi)
#pragma unroll
    for (int ni = 0; ni < 4; ++ni) acc[mi][ni] = (f32x4){0.f, 0.f, 0.f, 0.f};

  int g = ln >> 4;     // k-group 0..3
  int fr = ln & 15;

  for (int k0 = 0; k0 < DIN; k0 += 64) {
#pragma unroll
    for (int it = 0; it < 4; ++it) {
      int chunk = it * 4 + wv;             // 0..15, 8 rows each
      int ar = ar0 + chunk * 8;
      if (ar >= N_NODES) ar = N_NODES - 1;
      const unsigned short* asrc = &Ab[(long long)ar * DIN + k0 + scol];
      __builtin_amdgcn_global_load_lds(AS1(asrc), AS3(&As[chunk * 512]), 16, 0, 0);
      const unsigned short* bsrc = bbase + k0 + (long long)chunk * 8 * DIN;
      __builtin_amdgcn_global_load_lds(AS1(bsrc), AS3(&Bs[chunk * 512]), 16, 0, 0);
    }
    __syncthreads();

#pragma unroll
    for (int kk = 0; kk < 2; ++kk) {
      short8 af[4], bfr[4];
#pragma unroll
      for (int mi = 0; mi < 4; ++mi) {
        int r = wr * 64 + mi * 16 + fr;
        int slot = (kk * 4 + g) ^ (r & 7);
        af[mi] = *(const short8*)&As[r * 64 + slot * 8];
      }
#pragma unroll
      for (int ni = 0; ni < 4; ++ni) {
        int c = wc * 64 + ni * 16 + fr;
        int slot = (kk * 4 + g) ^ (c & 7);
        bfr[ni] = *(const short8*)&Bs[c * 64 + slot * 8];
      }
#pragma unroll
      for (int mi = 0; mi < 4; ++mi)
#pragma unroll
        for (int ni = 0; ni < 4; ++ni)
          acc[mi][ni] = __builtin_amdgcn_mfma_f32_16x16x32_bf16(af[mi], bfr[ni], acc[mi][ni], 0, 0, 0);
    }
    __syncthreads();
  }

  int fq = ln >> 4;
#pragma unroll
  for (int ni = 0; ni < 4; ++ni) {
    int colv = col0 + wc * 64 + ni * 16 + fr;
    float bv = bias[colv];
#pragma unroll
    for (int mi = 0; mi < 4; ++mi) {
#pragma unroll
      for (int j = 0; j < 4; ++j) {
        int row = row0 + wr * 64 + mi * 16 + fq * 4 + j;
        if (row < N_NODES)
          C[(long long)row * HID + colv] = f2bf(fmaxf(acc[mi][ni][j] + bv, 0.f));
      }
    }
  }
}

// ---------------- row norms from bf16 rows -> 1/max(||h_i||, eps) -----------
__global__ __launch_bounds__(256) void normBF(const unsigned short* __restrict__ hb,
                                              float* __restrict__ invn) {
  int w = (blockIdx.x * 256 + threadIdx.x) >> 6;
  int lane = threadIdx.x & 63;
  if (w >= N_NODES) return;
  us4 v = *(const us4*)&hb[(long long)w * HID + lane * 4];
  float x = bf2f(v.x), y = bf2f(v.y), z = bf2f(v.z), ww = bf2f(v.w);
  float s = x * x + y * y + z * z + ww * ww;
#pragma unroll
  for (int off = 32; off >= 1; off >>= 1) s += __shfl_xor(s, off);
  if (lane == 0) invn[w] = 1.0f / fmaxf(sqrtf(s), 1e-12f);
}

// fused AGNN conv: 1 wave/node, 4 edge-groups x 16 lanes, 16 feats/lane.
// v3: packed-f32 feature math (f32x2 pairs -> v_pk_fma_f32), 32-bit byte
// addressing, and 1-iteration software prefetch of {col, invn, row} so the
// dependent gather chain of it+1 overlaps compute of it. Scores bounded by
// |beta| (cosine) -> fixed-shift softmax, no online max.
__global__ __launch_bounds__(256) void convK(const unsigned short* __restrict__ hb,
                                             const float* __restrict__ invn,
                                             const int* __restrict__ row_ptr,
                                             const int* __restrict__ col,
                                             const float* __restrict__ beta_ptr,
                                             float* __restrict__ hout,
                                             unsigned short* __restrict__ hout_bf) {
  int w = (blockIdx.x * 256 + threadIdx.x) >> 6;
  int lane = threadIdx.x & 63;
  if (w >= N_NODES) return;
  int g = lane >> 4;    // edge-group 0..3
  int sub = lane & 15;  // feature slice [sub*16, sub*16+16)
  float beta = beta_ptr ? beta_ptr[0] : 1.0f;
  float babs = fabsf(beta);

  const char* hbase = (const char*)hb;
  unsigned ioff = (unsigned)w * (unsigned)(HID * 2) + (unsigned)sub * 32u;
  uint4 ia = *(const uint4*)(hbase + ioff);
  uint4 ib = *(const uint4*)(hbase + ioff + 16);
  float scale_i = invn[w] * beta;  // folded into hi once
  f32x2 hi[8];
  hi[0] = bfpair(ia.x) * scale_i; hi[1] = bfpair(ia.y) * scale_i;
  hi[2] = bfpair(ia.z) * scale_i; hi[3] = bfpair(ia.w) * scale_i;
  hi[4] = bfpair(ib.x) * scale_i; hi[5] = bfpair(ib.y) * scale_i;
  hi[6] = bfpair(ib.z) * scale_i; hi[7] = bfpair(ib.w) * scale_i;

  int e0 = row_ptr[w], e1 = row_ptr[w + 1];  // wave-uniform (SGPR)
  int nit = (e1 - e0 + 3) >> 2;              // >= 1 (self-loop)

  // prologue: prefetch iteration 0
  int ee0 = e0 + g;
  int s = col[ee0 < e1 ? ee0 : (e1 - 1)];
  float is = invn[s];
  unsigned off = (unsigned)s * (unsigned)(HID * 2) + (unsigned)sub * 32u;
  uint4 ja = *(const uint4*)(hbase + off);
  uint4 jb = *(const uint4*)(hbase + off + 16);

  float Z = 0.f;
  f32x2 acc[8];
#pragma unroll
  for (int q = 0; q < 8; ++q) acc[q] = (f32x2){0.f, 0.f};

  for (int it = 0; it < nit; ++it) {
    bool valid = (e0 + it * 4 + g) < e1;
    // prefetch it+1 (uniform branch: e0/e1/nit wave-uniform)
    int sn = s; float isn = is; uint4 jan = ja, jbn = jb;
    if (it + 1 < nit) {
      int een = e0 + (it + 1) * 4 + g;
      sn = col[een < e1 ? een : (e1 - 1)];
      isn = invn[sn];
      unsigned offn = (unsigned)sn * (unsigned)(HID * 2) + (unsigned)sub * 32u;
      jan = *(const uint4*)(hbase + offn);
      jbn = *(const uint4*)(hbase + offn + 16);
    }
    // unpack current row slice: 8 x f32x2 = 16 feats
    f32x2 hj[8];
    hj[0] = bfpair(ja.x); hj[1] = bfpair(ja.y);
    hj[2] = bfpair(ja.z); hj[3] = bfpair(ja.w);
    hj[4] = bfpair(jb.x); hj[5] = bfpair(jb.y);
    hj[6] = bfpair(jb.z); hj[7] = bfpair(jb.w);
    f32x2 d2 = (f32x2){0.f, 0.f};
#pragma unroll
    for (int q = 0; q < 8; ++q) d2 = FMA2(hi[q], hj[q], d2);
    float p = d2.x + d2.y;
    p += __shfl_xor(p, 1);
    p += __shfl_xor(p, 2);
    p += __shfl_xor(p, 4);
    p += __shfl_xor(p, 8);
    float sc = p * is;  // scale_i already folded into hi
    float wt = valid ? __expf(sc - babs) : 0.f;
    Z += wt;
    f32x2 w2 = (f32x2){wt, wt};
#pragma unroll
    for (int q = 0; q < 8; ++q) acc[q] = FMA2(w2, hj[q], acc[q]);
    s = sn; is = isn; ja = jan; jb = jbn;
  }

  // cross-group combine (4 partial vectors -> full sums in all lanes)
#pragma unroll
  for (int q = 0; q < 8; ++q) {
    acc[q].x += __shfl_xor(acc[q].x, 16);
    acc[q].x += __shfl_xor(acc[q].x, 32);
    acc[q].y += __shfl_xor(acc[q].y, 16);
    acc[q].y += __shfl_xor(acc[q].y, 32);
  }
  Z += __shfl_xor(Z, 16);
  Z += __shfl_xor(Z, 32);
  float r = 1.0f / Z;

  if (g == 0) {  // fp32 output, 64B/lane over 16 lanes = full 1KB row
    float* po = &hout[(long long)w * HID + sub * 16];
#pragma unroll
    for (int q4 = 0; q4 < 4; ++q4) {
      float4 o;
      o.x = acc[q4 * 2 + 0].x * r;
      o.y = acc[q4 * 2 + 0].y * r;
      o.z = acc[q4 * 2 + 1].x * r;
      o.w = acc[q4 * 2 + 1].y * r;
      *(float4*)&po[q4 * 4] = o;
    }
  } else if (g == 1 && hout_bf) {  // bf16 copy for next conv
    unsigned short* pb = &hout_bf[(long long)w * HID + sub * 16];
#pragma unroll
    for (int q4 = 0; q4 < 4; ++q4) {
      us4 ob;
      ob.x = f2bf(acc[q4 * 2 + 0].x * r);
      ob.y = f2bf(acc[q4 * 2 + 0].y * r);
      ob.z = f2bf(acc[q4 * 2 + 1].x * r);
      ob.w = f2bf(acc[q4 * 2 + 1].y * r);
      *(us4*)&pb[q4 * 4] = ob;
    }
  }
}

// ---------------- head: tiled GEMM (64x64 tile, K=256) + fused log-softmax ----
__global__ __launch_bounds__(256) void headK2(const float* __restrict__ Z,
                                              const float* __restrict__ W,
                                              const float* __restrict__ bias,
                                              float* __restrict__ out) {
  __shared__ float smem[2 * 32 * 68];
  float* As = smem;
  float* Bs = smem + 32 * 68;
  int t = threadIdx.x;
  int tx = t & 15, ty = t >> 4;
  int row0 = blockIdx.x * 64;
  float acc[4][4] = {};
  int lr = t >> 3;
  int lc4 = t & 7;

  for (int k0 = 0; k0 < HID; k0 += 32) {
#pragma unroll
    for (int rr = 0; rr < 64; rr += 32) {
      int gr = row0 + lr + rr;
      float4 va = (gr < N_NODES)
                      ? *(const float4*)&Z[(long long)gr * HID + k0 + lc4 * 4]
                      : make_float4(0.f, 0.f, 0.f, 0.f);
      As[(lc4 * 4 + 0) * 68 + lr + rr] = va.x;
      As[(lc4 * 4 + 1) * 68 + lr + rr] = va.y;
      As[(lc4 * 4 + 2) * 68 + lr + rr] = va.z;
      As[(lc4 * 4 + 3) * 68 + lr + rr] = va.w;
      int gc = lr + rr;
      float4 vb = *(const float4*)&W[(long long)gc * HID + k0 + lc4 * 4];
      Bs[(lc4 * 4 + 0) * 68 + lr + rr] = vb.x;
      Bs[(lc4 * 4 + 1) * 68 + lr + rr] = vb.y;
      Bs[(lc4 * 4 + 2) * 68 + lr + rr] = vb.z;
      Bs[(lc4 * 4 + 3) * 68 + lr + rr] = vb.w;
    }
    __syncthreads();
#pragma unroll
    for (int kk = 0; kk < 32; ++kk) {
      float4 a4 = *(const float4*)&As[kk * 68 + ty * 4];
      float4 b4 = *(const float4*)&Bs[kk * 68 + tx * 4];
      acc[0][0] += a4.x * b4.x; acc[0][1] += a4.x * b4.y; acc[0][2] += a4.x * b4.z; acc[0][3] += a4.x * b4.w;
      acc[1][0] += a4.y * b4.x; acc[1][1] += a4.y * b4.y; acc[1][2] += a4.y * b4.z; acc[1][3] += a4.y * b4.w;
      acc[2][0] += a4.z * b4.x; acc[2][1] += a4.z * b4.y; acc[2][2] += a4.z * b4.z; acc[2][3] += a4.z * b4.w;
      acc[3][0] += a4.w * b4.x; acc[3][1] += a4.w * b4.y; acc[3][2] += a4.w * b4.z; acc[3][3] += a4.w * b4.w;
    }
    __syncthreads();
  }

  float* ls = smem;
  float4 bv = *(const float4*)&bias[tx * 4];
#pragma unroll
  for (int r = 0; r < 4; ++r) {
    int lrow = ty * 4 + r;
    ls[lrow * 65 + tx * 4 + 0] = acc[r][0] + bv.x;
    ls[lrow * 65 + tx * 4 + 1] = acc[r][1] + bv.y;
    ls[lrow * 65 + tx * 4 + 2] = acc[r][2] + bv.z;
    ls[lrow * 65 + tx * 4 + 3] = acc[r][3] + bv.w;
  }
  __syncthreads();

  int wid = t >> 6, lane = t & 63;
#pragma unroll
  for (int rr2 = wid; rr2 < 64; rr2 += 4) {
    int node = row0 + rr2;
    if (node < N_NODES) {
      float v = ls[rr2 * 65 + lane];
      float mx = v;
#pragma unroll
      for (int off = 32; off >= 1; off >>= 1) mx = fmaxf(mx, __shfl_xor(mx, off));
      float ex = __expf(v - mx);
      float se = ex;
#pragma unroll
      for (int off = 32; off >= 1; off >>= 1) se += __shfl_xor(se, off);
      out[(long long)node * NOUT + lane] = v - mx - __logf(se);
    }
  }
}

extern "C" void kernel_launch(void* const* d_in, const int* in_sizes, int n_in,
                              void* d_out, int out_size, void* d_ws, size_t ws_size,
                              hipStream_t stream) {
  (void)in_sizes; (void)n_in; (void)out_size; (void)ws_size;
  const float* x = (const float*)d_in[0];
  const void* ei = d_in[1];
  const float* w1 = (const float*)d_in[2];
  const float* b1 = (const float*)d_in[3];
  const float* beta2 = (const float*)d_in[4];
  const float* w2 = (const float*)d_in[5];
  const float* b2 = (const float*)d_in[6];

  float* z1 = (float*)d_out;                       // [N, 256]
  float* z2 = z1 + (size_t)N_NODES * HID;          // [N, 256]
  float* lsm = z2 + (size_t)N_NODES * HID;         // [N, 64]

  unsigned short* h_bf = (unsigned short*)d_ws;             // [N,256] bf16
  unsigned short* z1_bf = h_bf + (size_t)N_NODES * HID;     // [N,256] bf16
  float* invn = (float*)(z1_bf + (size_t)N_NODES * HID);    // [N]
  int* row_ptr = (int*)(invn + N_NODES);                    // [N+1]
  int* cursor = row_ptr + N_NODES + 1;                      // [N]
  int* colv = cursor + N_NODES;                             // [ETOT]
  int* bsums = colv + ETOT;                                 // [<=64]
  int* flag = bsums + 64;                                   // [1]
  unsigned short* wb = (unsigned short*)(flag + 4);         // [256,512] bf16 w1

  // scratch bf16 x lives in the z2 output region (51.2 MB, exactly N*HID*4 B);
  // fully consumed by gemm1MF before convK#2 overwrites z2.
  unsigned short* xb = (unsigned short*)z2;                 // [N,512] bf16

  int nScan = (N_NODES + SCAN_CHUNK - 1) / SCAN_CHUNK;

  cvtK<<<2048, 256, 0, stream>>>(x, w1, xb, wb);
  initK<<<(N_NODES + 255) / 256, 256, 0, stream>>>(ei, cursor, flag);

  dim3 gg((N_NODES + 127) / 128, HID / 128);
  gemm1MF<<<gg, 256, 0, stream>>>(xb, wb, b1, h_bf);

  histK<<<(N_EDGES + 255) / 256, 256, 0, stream>>>(ei, flag, cursor);
  scan1K<<<nScan, 256, 0, stream>>>(cursor, row_ptr, bsums);
  scan2K<<<1, 64, 0, stream>>>(bsums, nScan);
  scan3K<<<(N_NODES + 255) / 256, 256, 0, stream>>>(row_ptr, bsums, cursor);
  scatterK<<<(N_EDGES + N_NODES + 255) / 256, 256, 0, stream>>>(ei, flag, cursor, colv);

  normBF<<<(N_NODES + 3) / 4, 256, 0, stream>>>(h_bf, invn);
  convK<<<(N_NODES + 3) / 4, 256, 0, stream>>>(h_bf, invn, row_ptr, colv, nullptr, z1, z1_bf);
  normBF<<<(N_NODES + 3) / 4, 256, 0, stream>>>(z1_bf, invn);
  convK<<<(N_NODES + 3) / 4, 256, 0, stream>>>(z1_bf, invn, row_ptr, colv, beta2, z2, nullptr);

  headK2<<<(N_NODES + 63) / 64, 256, 0, stream>>>(z2, w2, b2, lsm);
}

// Round 4
// 359.101 us; speedup vs baseline: 1.0291x; 1.0291x over previous
//
#include <hip/hip_runtime.h>

#define N_NODES 50000
#define N_EDGES 800000
#define ETOT (N_EDGES + N_NODES)
#define DIN 512
#define HID 256
#define NOUT 64
#define SCAN_CHUNK 2048

typedef __attribute__((ext_vector_type(8))) short short8;
typedef __attribute__((ext_vector_type(4))) float f32x4;
typedef __attribute__((ext_vector_type(2))) float f32x2;
typedef __attribute__((ext_vector_type(4))) unsigned short us4;

#define FMA2(a, b, c) __builtin_elementwise_fma((a), (b), (c))

// float -> bf16 bits, round-to-nearest-even
__device__ __forceinline__ unsigned short f2bf(float f) {
  union { float f; unsigned u; } x; x.f = f;
  unsigned r = x.u + 0x7fff + ((x.u >> 16) & 1);
  return (unsigned short)(r >> 16);
}
__device__ __forceinline__ float bf2f(unsigned short b) {
  return __uint_as_float(((unsigned)b) << 16);
}
// u32 holding bf16 pair {elem 2k (lo), elem 2k+1 (hi)} -> float2, 2 VALU ops
__device__ __forceinline__ f32x2 bfpair(unsigned u) {
  f32x2 r;
  r.x = __uint_as_float(u << 16);
  r.y = __uint_as_float(u & 0xffff0000u);
  return r;
}

// address-space casts for global_load_lds
#define AS1(p) ((const __attribute__((address_space(1))) unsigned int*)(p))
#define AS3(p) ((__attribute__((address_space(3))) unsigned int*)(p))

// ---------------- edge index decode (int32 vs int64 hedge) ----------------
__device__ __forceinline__ int edge_at(const void* ei, long long idx, int is32) {
  if (is32) return ((const int*)ei)[idx];
  return (int)((const long long*)ei)[idx];
}

// cursor[i]=1 (self-loop pre-count) + dtype detect (block 0, wave 0 scans
// 2048 int64 samples; lane 0 writes flag exactly once, 0 or 1).
__global__ void initK(const void* ei, int* cursor, int* flag) {
  int i = blockIdx.x * blockDim.x + threadIdx.x;
  if (i < N_NODES) cursor[i] = 1;
  if (blockIdx.x == 0 && threadIdx.x < 64) {
    int lane = threadIdx.x;
    bool bad = false;
#pragma unroll
    for (int j = 0; j < 32; ++j) {
      long long v = ((const long long*)ei)[lane * 32 + j];
      bad |= (v < 0 || v >= N_NODES);
    }
    bool anybad = __any(bad);
    if (lane == 0) *flag = anybad ? 1 : 0;
  }
}

__global__ void histK(const void* ei, const int* flag, int* cursor) {
  int e = blockIdx.x * blockDim.x + threadIdx.x;
  if (e >= N_EDGES) return;
  int f = *flag;
  int d = edge_at(ei, (long long)N_EDGES + e, f);
  atomicAdd(&cursor[d], 1);
}

// ---------------- exclusive scan over counts -> row_ptr ----------------
__global__ void scan1K(const int* counts, int* excl, int* bsums) {
  __shared__ int sdata[256];
  int base = blockIdx.x * SCAN_CHUNK;
  int t = threadIdx.x;
  int local[8];
  int sum = 0;
#pragma unroll
  for (int j = 0; j < 8; ++j) {
    int idx = base + t * 8 + j;
    int v = (idx < N_NODES) ? counts[idx] : 0;
    local[j] = sum;
    sum += v;
  }
  sdata[t] = sum;
  __syncthreads();
  for (int off = 1; off < 256; off <<= 1) {
    int v = (t >= off) ? sdata[t - off] : 0;
    __syncthreads();
    sdata[t] += v;
    __syncthreads();
  }
  int texcl = (t == 0) ? 0 : sdata[t - 1];
#pragma unroll
  for (int j = 0; j < 8; ++j) {
    int idx = base + t * 8 + j;
    if (idx < N_NODES) excl[idx] = texcl + local[j];
  }
  if (t == 255) bsums[blockIdx.x] = sdata[255];
}

__global__ void scan2K(int* bsums, int nb) {
  if (threadIdx.x == 0 && blockIdx.x == 0) {
    int run = 0;
    for (int i = 0; i < nb; ++i) { int v = bsums[i]; bsums[i] = run; run += v; }
  }
}

__global__ void scan3K(int* row_ptr, const int* bsums, int* cursor) {
  int i = blockIdx.x * blockDim.x + threadIdx.x;
  if (i < N_NODES) {
    int v = row_ptr[i] + bsums[i >> 11];
    row_ptr[i] = v;
    cursor[i] = v;
    if (i == 0) row_ptr[N_NODES] = ETOT;
  }
}

__global__ void scatterK(const void* ei, const int* flag, int* cursor, int* col) {
  int e = blockIdx.x * blockDim.x + threadIdx.x;
  if (e < N_EDGES) {
    int f = *flag;
    int s = edge_at(ei, e, f);
    int d = edge_at(ei, (long long)N_EDGES + e, f);
    int pos = atomicAdd(&cursor[d], 1);
    col[pos] = s;
  } else if (e < N_EDGES + N_NODES) {
    int i = e - N_EDGES;
    int pos = atomicAdd(&cursor[i], 1);
    col[pos] = i;
  }
}

// ---------------- fp32 -> bf16 streaming convert: x and w1 ----------------
__global__ __launch_bounds__(256) void cvtK(const float* __restrict__ x,
                                            const float* __restrict__ w1,
                                            unsigned short* __restrict__ xb,
                                            unsigned short* __restrict__ wb) {
  const long long NX = (long long)N_NODES * DIN / 8;  // chunks of 8 floats
  const long long NW = (long long)HID * DIN / 8;
  long long stride = (long long)gridDim.x * blockDim.x;
  for (long long c = (long long)blockIdx.x * blockDim.x + threadIdx.x;
       c < NX + NW; c += stride) {
    const float* src;
    unsigned short* dst;
    if (c < NX) { src = x + c * 8; dst = xb + c * 8; }
    else { src = w1 + (c - NX) * 8; dst = wb + (c - NX) * 8; }
    float4 v0 = ((const float4*)src)[0];
    float4 v1 = ((const float4*)src)[1];
    short8 s;
    s[0] = f2bf(v0.x); s[1] = f2bf(v0.y); s[2] = f2bf(v0.z); s[3] = f2bf(v0.w);
    s[4] = f2bf(v1.x); s[5] = f2bf(v1.y); s[6] = f2bf(v1.z); s[7] = f2bf(v1.w);
    *(short8*)dst = s;
  }
}

// ------- GEMM1 via MFMA from bf16 inputs: h_bf = bf16(relu(xb @ wb^T + b1)) ---
// m97 structure: 128x128 tile, BK=64, global_load_lds width=16 staging with
// pre-swizzled global source (rule #21): LDS linear dest, k-slot of lane =
// (lc ^ lr) so the swizzled ds_read (slot = kgrp ^ (r&7)) lands on the right
// data. Same XOR family as the round-0 kernel which measured 0 bank conflicts.
__global__ __launch_bounds__(256) void gemm1MF(const unsigned short* __restrict__ Ab,
                                               const unsigned short* __restrict__ Bb,
                                               const float* __restrict__ bias,
                                               unsigned short* __restrict__ C) {
  __shared__ short As[128 * 64];  // 16 KB, rows of 64 bf16, 8 slots x 16B
  __shared__ short Bs[128 * 64];
  int t = threadIdx.x;
  int wv = t >> 6, ln = t & 63;
  int wr = wv >> 1, wc = wv & 1;
  int row0 = blockIdx.x * 128;
  int col0 = blockIdx.y * 128;

  // staging: per wave-call, lane ln covers LDS bytes base + ln*16
  // = row (chunk*8 + ln>>3), slot (ln&7). Source fetches k-slot (lc ^ lr).
  int lr = ln >> 3, lc = ln & 7;
  int scol = ((lc ^ lr) << 3);  // element offset within 64-wide K-tile

  int ar0 = row0 + lr;  // + chunk*8 added per call
  const unsigned short* bbase = &Bb[(long long)(col0 + lr) * DIN + scol];

  f32x4 acc[4][4];
#pragma unroll
  for (int mi = 0; mi < 4; ++mi)
#pragma unroll
    for (int ni = 0; ni < 4; ++ni) acc[mi][ni] = (f32x4){0.f, 0.f, 0.f, 0.f};

  int g = ln >> 4;     // k-group 0..3
  int fr = ln & 15;

  for (int k0 = 0; k0 < DIN; k0 += 64) {
#pragma unroll
    for (int it = 0; it < 4; ++it) {
      int chunk = it * 4 + wv;             // 0..15, 8 rows each
      int ar = ar0 + chunk * 8;
      if (ar >= N_NODES) ar = N_NODES - 1;
      const unsigned short* asrc = &Ab[(long long)ar * DIN + k0 + scol];
      __builtin_amdgcn_global_load_lds(AS1(asrc), AS3(&As[chunk * 512]), 16, 0, 0);
      const unsigned short* bsrc = bbase + k0 + (long long)chunk * 8 * DIN;
      __builtin_amdgcn_global_load_lds(AS1(bsrc), AS3(&Bs[chunk * 512]), 16, 0, 0);
    }
    __syncthreads();

#pragma unroll
    for (int kk = 0; kk < 2; ++kk) {
      short8 af[4], bfr[4];
#pragma unroll
      for (int mi = 0; mi < 4; ++mi) {
        int r = wr * 64 + mi * 16 + fr;
        int slot = (kk * 4 + g) ^ (r & 7);
        af[mi] = *(const short8*)&As[r * 64 + slot * 8];
      }
#pragma unroll
      for (int ni = 0; ni < 4; ++ni) {
        int c = wc * 64 + ni * 16 + fr;
        int slot = (kk * 4 + g) ^ (c & 7);
        bfr[ni] = *(const short8*)&Bs[c * 64 + slot * 8];
      }
#pragma unroll
      for (int mi = 0; mi < 4; ++mi)
#pragma unroll
        for (int ni = 0; ni < 4; ++ni)
          acc[mi][ni] = __builtin_amdgcn_mfma_f32_16x16x32_bf16(af[mi], bfr[ni], acc[mi][ni], 0, 0, 0);
    }
    __syncthreads();
  }

  int fq = ln >> 4;
#pragma unroll
  for (int ni = 0; ni < 4; ++ni) {
    int colv = col0 + wc * 64 + ni * 16 + fr;
    float bv = bias[colv];
#pragma unroll
    for (int mi = 0; mi < 4; ++mi) {
#pragma unroll
      for (int j = 0; j < 4; ++j) {
        int row = row0 + wr * 64 + mi * 16 + fq * 4 + j;
        if (row < N_NODES)
          C[(long long)row * HID + colv] = f2bf(fmaxf(acc[mi][ni][j] + bv, 0.f));
      }
    }
  }
}

// ---------------- row norms from bf16 rows -> 1/max(||h_i||, eps) -----------
__global__ __launch_bounds__(256) void normBF(const unsigned short* __restrict__ hb,
                                              float* __restrict__ invn) {
  int w = (blockIdx.x * 256 + threadIdx.x) >> 6;
  int lane = threadIdx.x & 63;
  if (w >= N_NODES) return;
  us4 v = *(const us4*)&hb[(long long)w * HID + lane * 4];
  float x = bf2f(v.x), y = bf2f(v.y), z = bf2f(v.z), ww = bf2f(v.w);
  float s = x * x + y * y + z * z + ww * ww;
#pragma unroll
  for (int off = 32; off >= 1; off >>= 1) s += __shfl_xor(s, off);
  if (lane == 0) invn[w] = 1.0f / fmaxf(sqrtf(s), 1e-12f);
}

// fused AGNN conv: 1 wave/node, 4 edge-groups x 16 lanes, 16 feats/lane.
// v4: two-stage software pipeline over the 2-hop gather chain —
//   stage 1: col index fetched with a 2-iteration lead (affine address),
//   stage 2: invn+row for it+1 issued using a col that landed 1 iter ago.
// No load latency on the critical path except the prologue. Packed f32x2
// feature math (v_pk_fma_f32). Optional fused output-norm (invn_out) removes
// the separate normBF pass for the second conv.
__global__ __launch_bounds__(256) void convK(const unsigned short* __restrict__ hb,
                                             const float* __restrict__ invn,
                                             const int* __restrict__ row_ptr,
                                             const int* __restrict__ col,
                                             const float* __restrict__ beta_ptr,
                                             float* __restrict__ hout,
                                             unsigned short* __restrict__ hout_bf,
                                             float* __restrict__ invn_out) {
  int w = (blockIdx.x * 256 + threadIdx.x) >> 6;
  int lane = threadIdx.x & 63;
  if (w >= N_NODES) return;
  int g = lane >> 4;    // edge-group 0..3
  int sub = lane & 15;  // feature slice [sub*16, sub*16+16)
  float beta = beta_ptr ? beta_ptr[0] : 1.0f;
  float babs = fabsf(beta);

  const char* hbase = (const char*)hb;
  unsigned ioff = (unsigned)w * (unsigned)(HID * 2) + (unsigned)sub * 32u;
  uint4 ia = *(const uint4*)(hbase + ioff);
  uint4 ib = *(const uint4*)(hbase + ioff + 16);
  float scale_i = invn[w] * beta;  // folded into hi once
  f32x2 hi[8];
  hi[0] = bfpair(ia.x) * scale_i; hi[1] = bfpair(ia.y) * scale_i;
  hi[2] = bfpair(ia.z) * scale_i; hi[3] = bfpair(ia.w) * scale_i;
  hi[4] = bfpair(ib.x) * scale_i; hi[5] = bfpair(ib.y) * scale_i;
  hi[6] = bfpair(ib.z) * scale_i; hi[7] = bfpair(ib.w) * scale_i;

  int e0 = row_ptr[w], e1 = row_ptr[w + 1];  // wave-uniform (SGPR)
  int nit = (e1 - e0 + 3) >> 2;              // >= 1 (self-loop)
  int elast = e1 - 1;

  // prologue: col for it=0 and it=1; invn+row for it=0
  int ee0 = e0 + g;
  int c0 = col[ee0 < e1 ? ee0 : elast];
  int ee1 = e0 + 4 + g;
  int c1 = col[ee1 < e1 ? ee1 : elast];
  float is = invn[c0];
  unsigned off0 = (unsigned)c0 * (unsigned)(HID * 2) + (unsigned)sub * 32u;
  uint4 ja = *(const uint4*)(hbase + off0);
  uint4 jb = *(const uint4*)(hbase + off0 + 16);

  float Z = 0.f;
  f32x2 acc[8];
#pragma unroll
  for (int q = 0; q < 8; ++q) acc[q] = (f32x2){0.f, 0.f};

  for (int it = 0; it < nit; ++it) {
    bool valid = (e0 + it * 4 + g) < e1;
    // stage 1: fetch col for it+2 (address is affine, no dependence)
    int ee2 = e0 + (it + 2) * 4 + g;
    int c2 = col[ee2 < e1 ? ee2 : elast];
    // stage 2: invn + row for it+1 (c1 landed one iteration ago)
    float isn = invn[c1];
    unsigned offn = (unsigned)c1 * (unsigned)(HID * 2) + (unsigned)sub * 32u;
    uint4 jan = *(const uint4*)(hbase + offn);
    uint4 jbn = *(const uint4*)(hbase + offn + 16);
    // consume current row slice: 8 x f32x2 = 16 feats
    f32x2 hj[8];
    hj[0] = bfpair(ja.x); hj[1] = bfpair(ja.y);
    hj[2] = bfpair(ja.z); hj[3] = bfpair(ja.w);
    hj[4] = bfpair(jb.x); hj[5] = bfpair(jb.y);
    hj[6] = bfpair(jb.z); hj[7] = bfpair(jb.w);
    f32x2 d2 = (f32x2){0.f, 0.f};
#pragma unroll
    for (int q = 0; q < 8; ++q) d2 = FMA2(hi[q], hj[q], d2);
    float p = d2.x + d2.y;
    p += __shfl_xor(p, 1);
    p += __shfl_xor(p, 2);
    p += __shfl_xor(p, 4);
    p += __shfl_xor(p, 8);
    float sc = p * is;  // scale_i already folded into hi
    float wt = valid ? __expf(sc - babs) : 0.f;
    Z += wt;
    f32x2 w2 = (f32x2){wt, wt};
#pragma unroll
    for (int q = 0; q < 8; ++q) acc[q] = FMA2(w2, hj[q], acc[q]);
    // rotate pipeline registers
    c1 = c2; is = isn; ja = jan; jb = jbn;
  }

  // cross-group combine (4 partial vectors -> full sums in all lanes)
#pragma unroll
  for (int q = 0; q < 8; ++q) {
    acc[q].x += __shfl_xor(acc[q].x, 16);
    acc[q].x += __shfl_xor(acc[q].x, 32);
    acc[q].y += __shfl_xor(acc[q].y, 16);
    acc[q].y += __shfl_xor(acc[q].y, 32);
  }
  Z += __shfl_xor(Z, 16);
  Z += __shfl_xor(Z, 32);
  float r = 1.0f / Z;

  if (g == 0) {  // fp32 output, 64B/lane over 16 lanes = full 1KB row
    float* po = &hout[(long long)w * HID + sub * 16];
#pragma unroll
    for (int q4 = 0; q4 < 4; ++q4) {
      float4 o;
      o.x = acc[q4 * 2 + 0].x * r;
      o.y = acc[q4 * 2 + 0].y * r;
      o.z = acc[q4 * 2 + 1].x * r;
      o.w = acc[q4 * 2 + 1].y * r;
      *(float4*)&po[q4 * 4] = o;
    }
  } else if (g == 1 && hout_bf) {  // bf16 copy for next conv
    unsigned short* pb = &hout_bf[(long long)w * HID + sub * 16];
#pragma unroll
    for (int q4 = 0; q4 < 4; ++q4) {
      us4 ob;
      ob.x = f2bf(acc[q4 * 2 + 0].x * r);
      ob.y = f2bf(acc[q4 * 2 + 0].y * r);
      ob.z = f2bf(acc[q4 * 2 + 1].x * r);
      ob.w = f2bf(acc[q4 * 2 + 1].y * r);
      *(us4*)&pb[q4 * 4] = ob;
    }
  }

  // fused norm of the (bf16-rounded) output row -> invn for the next conv.
  // Matches normBF numerics: square the bf16-rounded values. Each lane holds
  // 16 feats; shfl_xor 1/2/4/8 sums across the 16-lane feature groups.
  if (invn_out) {
    float ss = 0.f;
#pragma unroll
    for (int q = 0; q < 8; ++q) {
      float vx = bf2f(f2bf(acc[q].x * r));
      float vy = bf2f(f2bf(acc[q].y * r));
      ss = fmaf(vx, vx, ss);
      ss = fmaf(vy, vy, ss);
    }
    ss += __shfl_xor(ss, 1);
    ss += __shfl_xor(ss, 2);
    ss += __shfl_xor(ss, 4);
    ss += __shfl_xor(ss, 8);
    if (lane == 0) invn_out[w] = 1.0f / fmaxf(sqrtf(ss), 1e-12f);
  }
}

// ---------------- head: tiled GEMM (64x64 tile, K=256) + fused log-softmax ----
__global__ __launch_bounds__(256) void headK2(const float* __restrict__ Z,
                                              const float* __restrict__ W,
                                              const float* __restrict__ bias,
                                              float* __restrict__ out) {
  __shared__ float smem[2 * 32 * 68];
  float* As = smem;
  float* Bs = smem + 32 * 68;
  int t = threadIdx.x;
  int tx = t & 15, ty = t >> 4;
  int row0 = blockIdx.x * 64;
  float acc[4][4] = {};
  int lr = t >> 3;
  int lc4 = t & 7;

  for (int k0 = 0; k0 < HID; k0 += 32) {
#pragma unroll
    for (int rr = 0; rr < 64; rr += 32) {
      int gr = row0 + lr + rr;
      float4 va = (gr < N_NODES)
                      ? *(const float4*)&Z[(long long)gr * HID + k0 + lc4 * 4]
                      : make_float4(0.f, 0.f, 0.f, 0.f);
      As[(lc4 * 4 + 0) * 68 + lr + rr] = va.x;
      As[(lc4 * 4 + 1) * 68 + lr + rr] = va.y;
      As[(lc4 * 4 + 2) * 68 + lr + rr] = va.z;
      As[(lc4 * 4 + 3) * 68 + lr + rr] = va.w;
      int gc = lr + rr;
      float4 vb = *(const float4*)&W[(long long)gc * HID + k0 + lc4 * 4];
      Bs[(lc4 * 4 + 0) * 68 + lr + rr] = vb.x;
      Bs[(lc4 * 4 + 1) * 68 + lr + rr] = vb.y;
      Bs[(lc4 * 4 + 2) * 68 + lr + rr] = vb.z;
      Bs[(lc4 * 4 + 3) * 68 + lr + rr] = vb.w;
    }
    __syncthreads();
#pragma unroll
    for (int kk = 0; kk < 32; ++kk) {
      float4 a4 = *(const float4*)&As[kk * 68 + ty * 4];
      float4 b4 = *(const float4*)&Bs[kk * 68 + tx * 4];
      acc[0][0] += a4.x * b4.x; acc[0][1] += a4.x * b4.y; acc[0][2] += a4.x * b4.z; acc[0][3] += a4.x * b4.w;
      acc[1][0] += a4.y * b4.x; acc[1][1] += a4.y * b4.y; acc[1][2] += a4.y * b4.z; acc[1][3] += a4.y * b4.w;
      acc[2][0] += a4.z * b4.x; acc[2][1] += a4.z * b4.y; acc[2][2] += a4.z * b4.z; acc[2][3] += a4.z * b4.w;
      acc[3][0] += a4.w * b4.x; acc[3][1] += a4.w * b4.y; acc[3][2] += a4.w * b4.z; acc[3][3] += a4.w * b4.w;
    }
    __syncthreads();
  }

  float* ls = smem;
  float4 bv = *(const float4*)&bias[tx * 4];
#pragma unroll
  for (int r = 0; r < 4; ++r) {
    int lrow = ty * 4 + r;
    ls[lrow * 65 + tx * 4 + 0] = acc[r][0] + bv.x;
    ls[lrow * 65 + tx * 4 + 1] = acc[r][1] + bv.y;
    ls[lrow * 65 + tx * 4 + 2] = acc[r][2] + bv.z;
    ls[lrow * 65 + tx * 4 + 3] = acc[r][3] + bv.w;
  }
  __syncthreads();

  int wid = t >> 6, lane = t & 63;
#pragma unroll
  for (int rr2 = wid; rr2 < 64; rr2 += 4) {
    int node = row0 + rr2;
    if (node < N_NODES) {
      float v = ls[rr2 * 65 + lane];
      float mx = v;
#pragma unroll
      for (int off = 32; off >= 1; off >>= 1) mx = fmaxf(mx, __shfl_xor(mx, off));
      float ex = __expf(v - mx);
      float se = ex;
#pragma unroll
      for (int off = 32; off >= 1; off >>= 1) se += __shfl_xor(se, off);
      out[(long long)node * NOUT + lane] = v - mx - __logf(se);
    }
  }
}

extern "C" void kernel_launch(void* const* d_in, const int* in_sizes, int n_in,
                              void* d_out, int out_size, void* d_ws, size_t ws_size,
                              hipStream_t stream) {
  (void)in_sizes; (void)n_in; (void)out_size; (void)ws_size;
  const float* x = (const float*)d_in[0];
  const void* ei = d_in[1];
  const float* w1 = (const float*)d_in[2];
  const float* b1 = (const float*)d_in[3];
  const float* beta2 = (const float*)d_in[4];
  const float* w2 = (const float*)d_in[5];
  const float* b2 = (const float*)d_in[6];

  float* z1 = (float*)d_out;                       // [N, 256]
  float* z2 = z1 + (size_t)N_NODES * HID;          // [N, 256]
  float* lsm = z2 + (size_t)N_NODES * HID;         // [N, 64]

  unsigned short* h_bf = (unsigned short*)d_ws;             // [N,256] bf16
  unsigned short* z1_bf = h_bf + (size_t)N_NODES * HID;     // [N,256] bf16
  float* invn = (float*)(z1_bf + (size_t)N_NODES * HID);    // [N]
  int* row_ptr = (int*)(invn + N_NODES);                    // [N+1]
  int* cursor = row_ptr + N_NODES + 1;                      // [N]
  int* colv = cursor + N_NODES;                             // [ETOT]
  int* bsums = colv + ETOT;                                 // [<=64]
  int* flag = bsums + 64;                                   // [1]
  unsigned short* wb = (unsigned short*)(flag + 4);         // [256,512] bf16 w1
  float* invn2 = (float*)(wb + (size_t)HID * DIN);          // [N]

  // scratch bf16 x lives in the z2 output region (51.2 MB, exactly N*HID*4 B);
  // fully consumed by gemm1MF before convK#2 overwrites z2.
  unsigned short* xb = (unsigned short*)z2;                 // [N,512] bf16

  int nScan = (N_NODES + SCAN_CHUNK - 1) / SCAN_CHUNK;

  cvtK<<<2048, 256, 0, stream>>>(x, w1, xb, wb);
  initK<<<(N_NODES + 255) / 256, 256, 0, stream>>>(ei, cursor, flag);

  dim3 gg((N_NODES + 127) / 128, HID / 128);
  gemm1MF<<<gg, 256, 0, stream>>>(xb, wb, b1, h_bf);

  histK<<<(N_EDGES + 255) / 256, 256, 0, stream>>>(ei, flag, cursor);
  scan1K<<<nScan, 256, 0, stream>>>(cursor, row_ptr, bsums);
  scan2K<<<1, 64, 0, stream>>>(bsums, nScan);
  scan3K<<<(N_NODES + 255) / 256, 256, 0, stream>>>(row_ptr, bsums, cursor);
  scatterK<<<(N_EDGES + N_NODES + 255) / 256, 256, 0, stream>>>(ei, flag, cursor, colv);

  normBF<<<(N_NODES + 3) / 4, 256, 0, stream>>>(h_bf, invn);
  convK<<<(N_NODES + 3) / 4, 256, 0, stream>>>(h_bf, invn, row_ptr, colv, nullptr, z1, z1_bf, invn2);
  convK<<<(N_NODES + 3) / 4, 256, 0, stream>>>(z1_bf, invn2, row_ptr, colv, beta2, z2, nullptr, nullptr);

  headK2<<<(N_NODES + 63) / 64, 256, 0, stream>>>(z2, w2, b2, lsm);
}